// Round 2
// baseline (551.549 us; speedup 1.0000x reference)
//
#include <hip/hip_runtime.h>

// S4 layer, MI355X. B=16, T=2048, H=1024, N=64.
// Pipeline (6 launches):
//   prep_k      : blk0/1 = Taylor expm(A*dtm) / expm(LCH*A*dtm) (1 wave, bf16 MFMA)
//                 blk2-9 = pack Wf = (B*dt) in B-fragment-major bf16
//                 blk10-17 = pack Cf = C in B-fragment-major bf16
//   gemm_u_k    : u = x @ W^T. NO LDS, NO barriers: A-frags loaded straight from
//                 global (rows are contiguous), B-frags from L2-resident Wf.
//   scan_local  : 64 chunks x 32 steps, zero-init local scans -> F_c  (I+R MFMA step)
//   scan_chunks : 1 wave, 64-step scan over chunk boundaries with A_L -> P_c
//   scan_final  : re-run chunks with init P_c, write all states (t*16+b, n) fp32
//   out_proj_k  : out = states @ C^T + D*x. NO LDS, NO barriers, same scheme.
// ws map (floats): [0]A_bar(4096) [4096]A_L(4096) [8192]Wf(32768=64Kbf16)
//   [40960]Cf(32768) [73728]F(65536) [139264]P(65536) [204800]u(2097152)
//   [2301952]states(2097152)  -> 17.6 MB total

#define H   1024
#define NS  64
#define NB  16
#define TT  2048
#define LCH 32
#define KCH 64

typedef __attribute__((ext_vector_type(8))) short bf16x8;
typedef __attribute__((ext_vector_type(4))) float f32x4;
typedef __attribute__((ext_vector_type(2))) unsigned int u32x2;

#define WS_ABAR 0
#define WS_AL   4096
#define WS_WF   8192
#define WS_CF   40960
#define WS_F    73728
#define WS_P    139264
#define WS_U    204800
#define WS_S    2301952

__device__ __forceinline__ unsigned short f2bf(float x) {
  union { float f; unsigned u; } v; v.f = x;
  unsigned r = (v.u + 0x7FFFu + ((v.u >> 16) & 1u)) >> 16;   // RNE
  return (unsigned short)r;
}

__device__ __forceinline__ bf16x8 packbf8(f32x4 a, f32x4 b) {
  bf16x8 r;
  r[0] = (short)f2bf(a[0]); r[1] = (short)f2bf(a[1]);
  r[2] = (short)f2bf(a[2]); r[3] = (short)f2bf(a[3]);
  r[4] = (short)f2bf(b[0]); r[5] = (short)f2bf(b[1]);
  r[6] = (short)f2bf(b[2]); r[7] = (short)f2bf(b[3]);
  return r;
}

__device__ __forceinline__ u32x2 packbf4(f32x4 v) {
  u32x2 r;
  r[0] = (unsigned)f2bf(v[0]) | ((unsigned)f2bf(v[1]) << 16);
  r[1] = (unsigned)f2bf(v[2]) | ((unsigned)f2bf(v[3]) << 16);
  return r;
}

__device__ __forceinline__ f32x4 mfma16(bf16x8 a, bf16x8 b, f32x4 c) {
  // D[m][n]: A lane holds A[m=lane&15][k=quad*8+j]; B holds B[k=quad*8+j][n=lane&15];
  // C/D: col=lane&15, row=quad*4+reg.  (verified correct in round 1)
  return __builtin_amdgcn_mfma_f32_16x16x32_bf16(a, b, c, 0, 0, 0);
}

// ---------------- prep: E = expm(scale*A), 1 wave, Taylor-12 via bf16 MFMA ----------------
__device__ void prep_block(const float* Ain, const float* ldt, float* ws, int which) {
  __shared__ float Mb[64 * 68];
  __shared__ short Tl[64 * 72];
  const int lane = threadIdx.x;
  const int cq = lane >> 4, cl = lane & 15;

  float s = 0.f;
  for (int j = 0; j < 16; ++j) s += expf(ldt[lane + j * 64]);
  for (int off = 32; off; off >>= 1) s += __shfl_down(s, off);
  float dtm = __shfl(s, 0) * (1.0f / 1024.0f);
  float scale = which ? dtm * (float)LCH : dtm;

  for (int idx = lane; idx < 4096; idx += 64) {
    int r = idx >> 6, c = idx & 63;
    float v = Ain[idx] * scale;
    Mb[c * 68 + r] = v;
    Tl[r * 72 + c] = (short)f2bf(v);
  }

  float E[16][4];
  for (int mt = 0; mt < 4; ++mt)
    for (int nt = 0; nt < 4; ++nt)
      for (int r = 0; r < 4; ++r) {
        int row = mt * 16 + cq * 4 + r, col = nt * 16 + cl;
        E[mt * 4 + nt][r] = (row == col ? 1.f : 0.f) + Ain[row * 64 + col] * scale;
      }

  __asm volatile("s_waitcnt lgkmcnt(0)" ::: "memory");

  for (int it = 2; it <= 12; ++it) {
    bf16x8 af[4][2];
    for (int mt = 0; mt < 4; ++mt)
      for (int kh = 0; kh < 2; ++kh)
        af[mt][kh] = *(const bf16x8*)&Tl[(mt * 16 + cl) * 72 + kh * 32 + cq * 8];
    float inv = 1.0f / (float)it;
    bf16x8 bfr[4][2];
    for (int nt = 0; nt < 4; ++nt)
      for (int kh = 0; kh < 2; ++kh) {
        const float* p = &Mb[(nt * 16 + cl) * 68 + kh * 32 + cq * 8];
        f32x4 a = *(const f32x4*)p;
        f32x4 b = *(const f32x4*)(p + 4);
        bfr[nt][kh] = packbf8(a * inv, b * inv);
      }
    f32x4 zero = {0.f, 0.f, 0.f, 0.f};
    f32x4 acc[16];
    for (int i = 0; i < 16; ++i) acc[i] = zero;
    for (int mt = 0; mt < 4; ++mt)
      for (int nt = 0; nt < 4; ++nt) {
        acc[mt * 4 + nt] = mfma16(af[mt][0], bfr[nt][0], acc[mt * 4 + nt]);
        acc[mt * 4 + nt] = mfma16(af[mt][1], bfr[nt][1], acc[mt * 4 + nt]);
      }
    __asm volatile("s_waitcnt lgkmcnt(0)" ::: "memory");
    for (int mt = 0; mt < 4; ++mt)
      for (int nt = 0; nt < 4; ++nt)
        for (int r = 0; r < 4; ++r) {
          float t = acc[mt * 4 + nt][r];
          E[mt * 4 + nt][r] += t;
          Tl[(mt * 16 + cq * 4 + r) * 72 + nt * 16 + cl] = (short)f2bf(t);
        }
    __asm volatile("s_waitcnt lgkmcnt(0)" ::: "memory");
  }

  float* dst = ws + (which ? WS_AL : WS_ABAR);
  for (int mt = 0; mt < 4; ++mt)
    for (int nt = 0; nt < 4; ++nt)
      for (int r = 0; r < 4; ++r)
        dst[(mt * 16 + cq * 4 + r) * 64 + nt * 16 + cl] = E[mt * 4 + nt][r];
}

// Wf[f]: f = (((hc*4+nt)*4+quad)*16+cl)*8+j ; value = B[n=nt*16+cl][h=hc*32+quad*8+j]*dt[h]
// Cf[f]: f = (((ht*2+kc)*4+quad)*16+cl)*8+j ; value = C[h=ht*16+cl][n=kc*32+quad*8+j]
__global__ __launch_bounds__(256) void prep_k(const float* Ain, const float* Bm,
                                              const float* Cm, const float* ldt, float* ws) {
  const int bid = blockIdx.x;
  if (bid < 2) {
    if (threadIdx.x < 64) prep_block(Ain, ldt, ws, bid);
    return;
  }
  if (bid < 10) {
    unsigned short* wf = (unsigned short*)(ws + WS_WF);
    int tg = (bid - 2) * 256 + threadIdx.x;
    int f0 = tg * 32;
    for (int i = 0; i < 32; ++i) {
      int f = f0 + i;
      int j = f & 7, cl = (f >> 3) & 15, quad = (f >> 7) & 3, nt = (f >> 9) & 3, hc = f >> 11;
      int n = nt * 16 + cl, h = hc * 32 + quad * 8 + j;
      wf[f] = f2bf(Bm[n * 1024 + h] * expf(ldt[h]));
    }
  } else {
    unsigned short* cf = (unsigned short*)(ws + WS_CF);
    int tg = (bid - 10) * 256 + threadIdx.x;
    int f0 = tg * 32;
    for (int i = 0; i < 32; ++i) {
      int f = f0 + i;
      int j = f & 7, cl = (f >> 3) & 15, quad = (f >> 7) & 3, kc = (f >> 9) & 1, ht = f >> 10;
      int h = ht * 16 + cl, n = kc * 32 + quad * 8 + j;
      cf[f] = f2bf(Cm[h * 64 + n]);
    }
  }
}

// ---------------- u = x @ W^T : no LDS, no barriers ----------------
// wave m-tile = 16 x-rows (natural order g=b*T+t); lane(quad,cl): A row = base+cl.
__global__ __launch_bounds__(256) void gemm_u_k(const float* x, float* ws) {
  const unsigned short* wf = (const unsigned short*)(ws + WS_WF);
  float* u2 = ws + WS_U;
  const int tid = threadIdx.x;
  const int wid = tid >> 6, lane = tid & 63;
  const int quad = lane >> 4, cl = lane & 15;
  const int mt = blockIdx.x * 4 + wid;
  const int bt0w = mt * 16;

  const float* xrow = x + (long)(bt0w + cl) * H + quad * 8;
  f32x4 zero = {0.f, 0.f, 0.f, 0.f};
  f32x4 acc[4];
  for (int i = 0; i < 4; ++i) acc[i] = zero;

#pragma unroll 4
  for (int hc = 0; hc < 32; ++hc) {
    f32x4 xa = *(const f32x4*)(xrow + hc * 32);
    f32x4 xb = *(const f32x4*)(xrow + hc * 32 + 4);
    bf16x8 af = packbf8(xa, xb);
    for (int nt = 0; nt < 4; ++nt) {
      bf16x8 bfr = *(const bf16x8*)&wf[((hc * 16 + nt * 4 + quad) * 16 + cl) * 8];
      acc[nt] = mfma16(af, bfr, acc[nt]);
    }
  }
  // store: D row m=quad*4+reg -> x row g=bt0w+m -> u2 row (t*16+b), t=g&2047, b=g>>11
  for (int nt = 0; nt < 4; ++nt)
    for (int r = 0; r < 4; ++r) {
      int g = bt0w + quad * 4 + r;
      int t = g & (TT - 1), b = g >> 11;
      u2[(long)(t * 16 + b) * 64 + nt * 16 + cl] = acc[nt][r];
    }
}

// ---------------- scan step: Z_new = (I+R) @ Z + U  (Z is N x B, C/D layout) ----------------
__device__ __forceinline__ void load_RF(const float* Amat, bf16x8 Rf[4][2], int cq, int cl) {
  for (int mt = 0; mt < 4; ++mt)
    for (int kh = 0; kh < 2; ++kh) {
      int m = mt * 16 + cl;
      int kb = kh * 32 + cq * 8;
      f32x4 v0 = *(const f32x4*)&Amat[m * 64 + kb];
      f32x4 v1 = *(const f32x4*)&Amat[m * 64 + kb + 4];
      for (int j = 0; j < 4; ++j) {
        if (m == kb + j) v0[j] -= 1.f;
        if (m == kb + 4 + j) v1[j] -= 1.f;
      }
      Rf[mt][kh] = packbf8(v0, v1);
    }
}

__device__ __forceinline__ void scan_step(f32x4 Z[4], const bf16x8 Rf[4][2], short* Zl,
                                          const f32x4 U[4], int cq, int cl) {
  for (int t = 0; t < 4; ++t)
    *(u32x2*)&Zl[cl * 72 + t * 16 + cq * 4] = packbf4(Z[t]);
  __asm volatile("s_waitcnt lgkmcnt(0)" ::: "memory");
  bf16x8 zf0 = *(const bf16x8*)&Zl[cl * 72 + cq * 8];
  bf16x8 zf1 = *(const bf16x8*)&Zl[cl * 72 + 32 + cq * 8];
  for (int t = 0; t < 4; ++t) Z[t] += U[t];
  for (int mt = 0; mt < 4; ++mt) {
    Z[mt] = mfma16(Rf[mt][0], zf0, Z[mt]);
    Z[mt] = mfma16(Rf[mt][1], zf1, Z[mt]);
  }
}

__global__ __launch_bounds__(64) void scan_local_k(float* ws) {
  const float* Abar = ws + WS_ABAR;
  const float* u2 = ws + WS_U;
  float* F = ws + WS_F;
  __shared__ short Zl[16 * 72];
  const int lane = threadIdx.x, cq = lane >> 4, cl = lane & 15;
  const int c = blockIdx.x;
  bf16x8 Rf[4][2];
  load_RF(Abar, Rf, cq, cl);
  f32x4 zero = {0.f, 0.f, 0.f, 0.f};
  f32x4 Z[4], U0[4], U1[4], Un[4];
  for (int t = 0; t < 4; ++t) Z[t] = zero;
  const float* ub = u2 + (long)c * LCH * 1024 + cl * 64 + cq * 4;
  for (int t = 0; t < 4; ++t) U0[t] = *(const f32x4*)(ub + t * 16);
  for (int t = 0; t < 4; ++t) U1[t] = *(const f32x4*)(ub + 1024 + t * 16);
  for (int ti = 0; ti < LCH; ++ti) {
    const float* un = ub + (ti + 2) * 1024;   // 2-deep prefetch (overrun lands in ws, harmless)
    for (int t = 0; t < 4; ++t) Un[t] = *(const f32x4*)(un + t * 16);
    scan_step(Z, Rf, Zl, U0, cq, cl);
    for (int t = 0; t < 4; ++t) { U0[t] = U1[t]; U1[t] = Un[t]; }
  }
  for (int t = 0; t < 4; ++t)
    *(f32x4*)&F[(long)c * 1024 + cl * 64 + t * 16 + cq * 4] = Z[t];
}

__global__ __launch_bounds__(64) void scan_chunks_k(float* ws) {
  const float* AL = ws + WS_AL;
  const float* F = ws + WS_F;
  float* P = ws + WS_P;
  __shared__ short Zl[16 * 72];
  const int lane = threadIdx.x, cq = lane >> 4, cl = lane & 15;
  bf16x8 Rf[4][2];
  load_RF(AL, Rf, cq, cl);
  f32x4 zero = {0.f, 0.f, 0.f, 0.f};
  f32x4 Z[4], U0[4], U1[4], Un[4];
  for (int t = 0; t < 4; ++t) Z[t] = zero;
  const float* fb = F + cl * 64 + cq * 4;
  for (int t = 0; t < 4; ++t) U0[t] = *(const f32x4*)(fb + t * 16);
  for (int t = 0; t < 4; ++t) U1[t] = *(const f32x4*)(fb + 1024 + t * 16);
  for (int c = 0; c < KCH; ++c) {
    long off = (long)c * 1024 + cl * 64 + cq * 4;
    for (int t = 0; t < 4; ++t) *(f32x4*)&P[off + t * 16] = Z[t];   // P_c before update
    const float* fn = fb + (c + 2) * 1024;
    for (int t = 0; t < 4; ++t) Un[t] = *(const f32x4*)(fn + t * 16);
    scan_step(Z, Rf, Zl, U0, cq, cl);
    for (int t = 0; t < 4; ++t) { U0[t] = U1[t]; U1[t] = Un[t]; }
  }
}

__global__ __launch_bounds__(64) void scan_final_k(float* ws) {
  const float* Abar = ws + WS_ABAR;
  const float* u2 = ws + WS_U;
  const float* P = ws + WS_P;
  float* S2 = ws + WS_S;
  __shared__ short Zl[16 * 72];
  const int lane = threadIdx.x, cq = lane >> 4, cl = lane & 15;
  const int c = blockIdx.x;
  bf16x8 Rf[4][2];
  load_RF(Abar, Rf, cq, cl);
  f32x4 Z[4], U0[4], U1[4], Un[4];
  long poff = (long)c * 1024 + cl * 64 + cq * 4;
  for (int t = 0; t < 4; ++t) Z[t] = *(const f32x4*)&P[poff + t * 16];
  const float* ub = u2 + (long)c * LCH * 1024 + cl * 64 + cq * 4;
  float* sb = S2 + (long)c * LCH * 1024 + cl * 64 + cq * 4;
  for (int t = 0; t < 4; ++t) U0[t] = *(const f32x4*)(ub + t * 16);
  for (int t = 0; t < 4; ++t) U1[t] = *(const f32x4*)(ub + 1024 + t * 16);
  for (int ti = 0; ti < LCH; ++ti) {
    const float* un = ub + (ti + 2) * 1024;
    for (int t = 0; t < 4; ++t) Un[t] = *(const f32x4*)(un + t * 16);
    scan_step(Z, Rf, Zl, U0, cq, cl);
    float* so = sb + ti * 1024;
    for (int t = 0; t < 4; ++t) *(f32x4*)(so + t * 16) = Z[t];
    for (int t = 0; t < 4; ++t) { U0[t] = U1[t]; U1[t] = Un[t]; }
  }
}

// ---------------- out = states @ C^T + D*x : no LDS, no barriers ----------------
// wave m-tile = 16 states-rows (order s=t*16+b, 16-aligned => t=mt const, b=quad*4+reg)
// wave h-span = 256 (16 nt tiles).
__global__ __launch_bounds__(256) void out_proj_k(const float* ws, const float* Dv,
                                                  const float* x, float* out) {
  const float* S2 = ws + WS_S;
  const unsigned short* cf = (const unsigned short*)(ws + WS_CF);
  const int tid = threadIdx.x;
  const int bid = blockIdx.x;
  const int rg = bid & 511, hg = bid >> 9;
  const int wid = tid >> 6, lane = tid & 63;
  const int quad = lane >> 4, cl = lane & 15;
  const int mt = rg * 4 + wid;          // == t index (s0 = mt*16)
  const int s0 = mt * 16;
  const int h0 = hg * 256;

  // A-frags straight from global: states row s0+cl is 64 contiguous floats
  const float* sr = S2 + (long)(s0 + cl) * 64 + quad * 8;
  f32x4 a00 = *(const f32x4*)(sr);
  f32x4 a01 = *(const f32x4*)(sr + 4);
  f32x4 a10 = *(const f32x4*)(sr + 32);
  f32x4 a11 = *(const f32x4*)(sr + 36);
  bf16x8 af0 = packbf8(a00, a01);
  bf16x8 af1 = packbf8(a10, a11);

  f32x4 zero = {0.f, 0.f, 0.f, 0.f};
  const int t = mt;
  for (int nt = 0; nt < 16; ++nt) {
    int htg = (h0 >> 4) + nt;
    bf16x8 b0 = *(const bf16x8*)&cf[(((htg * 2 + 0) * 4 + quad) * 16 + cl) * 8];
    bf16x8 b1 = *(const bf16x8*)&cf[(((htg * 2 + 1) * 4 + quad) * 16 + cl) * 8];
    f32x4 acc = zero;
    acc = mfma16(af0, b0, acc);
    acc = mfma16(af1, b1, acc);
    int h = h0 + nt * 16 + cl;
    float d = Dv[h];
    for (int r = 0; r < 4; ++r) {
      int b = quad * 4 + r;                     // D row m=quad*4+r -> s=s0+m -> b=m (t const)
      long idx = ((long)b * TT + t) * H + h;
      out[idx] = acc[r] + d * x[idx];
    }
  }
}

extern "C" void kernel_launch(void* const* d_in, const int* in_sizes, int n_in,
                              void* d_out, int out_size, void* d_ws, size_t ws_size,
                              hipStream_t stream) {
  const float* x = (const float*)d_in[0];
  const float* A = (const float*)d_in[1];
  const float* Bm = (const float*)d_in[2];
  const float* Cm = (const float*)d_in[3];
  const float* Dv = (const float*)d_in[4];
  const float* ldt = (const float*)d_in[5];
  float* out = (float*)d_out;
  float* ws = (float*)d_ws;

  prep_k<<<dim3(18), dim3(256), 0, stream>>>(A, Bm, Cm, ldt, ws);
  gemm_u_k<<<dim3(512), dim3(256), 0, stream>>>(x, ws);
  scan_local_k<<<dim3(KCH), dim3(64), 0, stream>>>(ws);
  scan_chunks_k<<<dim3(1), dim3(64), 0, stream>>>(ws);
  scan_final_k<<<dim3(KCH), dim3(64), 0, stream>>>(ws);
  out_proj_k<<<dim3(2048), dim3(256), 0, stream>>>(ws, Dv, x, out);
}